// Round 11
// baseline (60.550 us; speedup 1.0000x reference)
//
#include <hip/hip_runtime.h>
#include <hip/hip_fp16.h>
#include <math.h>

#define DEV static __device__ __forceinline__

typedef float f32x4 __attribute__((ext_vector_type(4)));
typedef _Float16 f16x8 __attribute__((ext_vector_type(8)));

DEV _Float16 f2h(float x) { return (_Float16)x; }

DEV f16x8 ld_cvt8(const float* __restrict__ p) {
  const float4 a = *(const float4*)p;
  const float4 b = *(const float4*)(p + 4);
  f16x8 r;
  r[0] = f2h(a.x); r[1] = f2h(a.y); r[2] = f2h(a.z); r[3] = f2h(a.w);
  r[4] = f2h(b.x); r[5] = f2h(b.y); r[6] = f2h(b.z); r[7] = f2h(b.w);
  return r;
}

DEV float wave_sum64(float v) {
  v += __shfl_xor(v, 32, 64);
  v += __shfl_xor(v, 16, 64);
  v += __shfl_xor(v, 8, 64);
  v += __shfl_xor(v, 4, 64);
  v += __shfl_xor(v, 2, 64);
  v += __shfl_xor(v, 1, 64);
  return v;
}

// Fragment convention (validated R5-R8):
//   A[m = l&15][k = kc*32 + (l>>4)*8 + j], B[k][n = l&15],
//   D[m = (l>>4)*4 + r][n = l&15].
// B LDS layout: Bl[((kc*4 + nt)*64 + lg*16 + (n&15))*8 + jj]

// ---------------------------------------------------------------------------
// K1 fused: blocks [0,NPACK): pack | [NPACK,+NATT): q/K/V proj | tail: B1 fold.
// Unchanged from R8 (validated).
// ---------------------------------------------------------------------------
__global__ __launch_bounds__(512)
void k_front(const int* __restrict__ relations, const int* __restrict__ entity_pairs,
             const int* __restrict__ train_edges,
             const int* __restrict__ entity2edges, const int* __restrict__ edge2entities,
             const int* __restrict__ edge2relation,
             const float* __restrict__ rel_emb, const float* __restrict__ w_ent0,
             const int* __restrict__ user_ids, const int* __restrict__ top_k_ids,
             const float* __restrict__ user_emb, const float* __restrict__ ent_emb,
             const float* __restrict__ wq, const float* __restrict__ bq,
             const float* __restrict__ wk, const float* __restrict__ bk,
             const float* __restrict__ wv, const float* __restrict__ bv,
             _Float16* __restrict__ Xacc, int* __restrict__ idx,
             int* __restrict__ rsel_arr, float* __restrict__ B1,
             float* __restrict__ qout, _Float16* __restrict__ kkb,
             _Float16* __restrict__ vvb, int bs, int npack, int natt)
{
  __shared__ __align__(16) unsigned char smem[24576];
  const int lane = threadIdx.x & 63;
  const int wid = threadIdx.x >> 6;

  if ((int)blockIdx.x < npack) {
    // ---------------- pack role ----------------
    const int w = blockIdx.x * 8 + wid;
    const int b = w >> 2;
    const int q = w & 3;
    if (b >= bs) return;

    const int te = __builtin_amdgcn_readfirstlane(train_edges[b]);
    const int n0p = __builtin_amdgcn_readfirstlane(entity_pairs[b * 2 + 0]);
    const int n1p = __builtin_amdgcn_readfirstlane(entity_pairs[b * 2 + 1]);

    const int l5 = lane & 31;
    const int ent0 = (l5 >> 4) ? n1p : n0p;
    const int e0 = entity2edges[ent0 * 16 + (l5 & 15)];
    const int r0 = edge2relation[e0];

    const int itemBase = b * 33;

    int na0[4], na1[4], nb0[4], nb1[4];
#pragma unroll
    for (int t = 0; t < 4; ++t) {
      const int j0 = q * 8 + 2 * t;
      const int ea = __builtin_amdgcn_readlane(e0, j0);
      const int eb = __builtin_amdgcn_readlane(e0, j0 + 1);
      na0[t] = __builtin_amdgcn_readfirstlane(edge2entities[ea * 2 + 0]);
      na1[t] = __builtin_amdgcn_readfirstlane(edge2entities[ea * 2 + 1]);
      nb0[t] = __builtin_amdgcn_readfirstlane(edge2entities[eb * 2 + 0]);
      nb1[t] = __builtin_amdgcn_readfirstlane(edge2entities[eb * 2 + 1]);
    }
    int e_[4];
#pragma unroll
    for (int t = 0; t < 4; ++t) {
      const int ent = (lane < 16) ? na0[t] : (lane < 32) ? na1[t]
                    : (lane < 48) ? nb0[t] : nb1[t];
      e_[t] = entity2edges[ent * 16 + (lane & 15)];
    }
    unsigned long long bal_[4];
    int r_[4];
#pragma unroll
    for (int t = 0; t < 4; ++t) {
      const bool keep = (e_[t] != te);
      bal_[t] = __ballot(keep);
      const int rr = edge2relation[e_[t]];
      r_[t] = keep ? rr : 64;
    }
#pragma unroll
    for (int t = 0; t < 4; ++t) {
      int ha0 = 0, ha1 = 0, hb0 = 0, hb1 = 0;
#pragma unroll
      for (int s = 0; s < 16; ++s) {
        ha0 += (__builtin_amdgcn_readlane(r_[t], s) == lane) ? 1 : 0;
        ha1 += (__builtin_amdgcn_readlane(r_[t], s + 16) == lane) ? 1 : 0;
        hb0 += (__builtin_amdgcn_readlane(r_[t], s + 32) == lane) ? 1 : 0;
        hb1 += (__builtin_amdgcn_readlane(r_[t], s + 48) == lane) ? 1 : 0;
      }
      const int ca0 = __popcll(bal_[t] & 0xFFFFull);
      const int ca1 = __popcll(bal_[t] & 0xFFFF0000ull);
      const int cb0 = __popcll(bal_[t] & 0xFFFF00000000ull);
      const int cb1 = __popcll(bal_[t] >> 48);
      const int j0 = q * 8 + 2 * t;
      const int it0 = itemBase + j0, it1 = it0 + 1;
      Xacc[(size_t)(2 * it0 + 0) * 64 + lane] = f2h((float)ha0 / (float)(ca0 ? ca0 : 1));
      Xacc[(size_t)(2 * it0 + 1) * 64 + lane] = f2h((float)ha1 / (float)(ca1 ? ca1 : 1));
      Xacc[(size_t)(2 * it1 + 0) * 64 + lane] = f2h((float)hb0 / (float)(cb0 ? cb0 : 1));
      Xacc[(size_t)(2 * it1 + 1) * 64 + lane] = f2h((float)hb1 / (float)(cb1 ? cb1 : 1));
      if (lane == 0) {
        idx[2 * it0 + 0] = na0[t]; idx[2 * it0 + 1] = na1[t];
        idx[2 * it1 + 0] = nb0[t]; idx[2 * it1 + 1] = nb1[t];
        rsel_arr[it0] = __builtin_amdgcn_readlane(r0, j0);
        rsel_arr[it1] = __builtin_amdgcn_readlane(r0, j0 + 1);
      }
    }
    if (q == 3) {
      const int it = itemBase + 32;
      const bool keep0 = (e0 != te);
      const unsigned long long bal0 = __ballot(keep0);
      const int r0m = keep0 ? r0 : 64;
      int h0 = 0, h1 = 0;
#pragma unroll
      for (int s = 0; s < 16; ++s) {
        h0 += (__builtin_amdgcn_readlane(r0m, s) == lane) ? 1 : 0;
        h1 += (__builtin_amdgcn_readlane(r0m, s + 16) == lane) ? 1 : 0;
      }
      const int c0 = __popcll(bal0 & 0xFFFFull);
      const int c1 = __popcll(bal0 & 0xFFFF0000ull);
      Xacc[(size_t)(2 * it + 0) * 64 + lane] = f2h((float)h0 / (float)(c0 ? c0 : 1));
      Xacc[(size_t)(2 * it + 1) * 64 + lane] = f2h((float)h1 / (float)(c1 ? c1 : 1));
      if (lane == 0) {
        idx[2 * it + 0] = n0p;
        idx[2 * it + 1] = n1p;
        rsel_arr[it] = relations[b];
      }
    }
    return;
  }

  if ((int)blockIdx.x < npack + natt) {
    // ---------------- attention q/K/V projection role ----------------
    _Float16* Bq = (_Float16*)smem;
    _Float16* Bk = Bq + 4096;
    _Float16* Bv = Bq + 8192;
    for (int t = threadIdx.x; t < 4096; t += 512) {
      const int k = t >> 6, n = t & 63;
      const int kc = k >> 5, lg2 = (k >> 3) & 3, jj = k & 7;
      const int nt = n >> 4, ln = lg2 * 16 + (n & 15);
      const int off = ((kc * 4 + nt) * 64 + ln) * 8 + jj;
      Bq[off] = f2h(wq[t]); Bk[off] = f2h(wk[t]); Bv[off] = f2h(wv[t]);
    }
    __syncthreads();

    const int row0 = (((int)blockIdx.x - npack) * 8 + wid) * 16;
    if (row0 >= bs * 11) return;
    const int l15 = lane & 15, lg = lane >> 4;

    if (row0 < bs) {
      const int uid = user_ids[row0 + l15];
      float bs4[4];
#pragma unroll
      for (int nt = 0; nt < 4; ++nt) bs4[nt] = bq[nt * 16 + l15];
      f32x4 acc[4];
#pragma unroll
      for (int nt = 0; nt < 4; ++nt) acc[nt] = (f32x4)(0.f);
#pragma unroll
      for (int kc = 0; kc < 2; ++kc) {
        const f16x8 A = ld_cvt8(user_emb + (size_t)uid * 64 + kc * 32 + lg * 8);
#pragma unroll
        for (int nt = 0; nt < 4; ++nt) {
          const f16x8 Bf = *(const f16x8*)&Bq[((kc * 4 + nt) * 64 + lane) * 8];
          acc[nt] = __builtin_amdgcn_mfma_f32_16x16x32_f16(A, Bf, acc[nt], 0, 0, 0);
        }
      }
#pragma unroll
      for (int nt = 0; nt < 4; ++nt)
#pragma unroll
        for (int r = 0; r < 4; ++r)
          qout[(size_t)(row0 + lg * 4 + r) * 64 + nt * 16 + l15] = acc[nt][r] + bs4[nt];
    } else {
      const int r2 = row0 - bs + l15;
      const int tid = top_k_ids[r2];
      float bsk[4], bsv[4];
#pragma unroll
      for (int nt = 0; nt < 4; ++nt) { bsk[nt] = bk[nt * 16 + l15]; bsv[nt] = bv[nt * 16 + l15]; }
      f32x4 ak[4], av[4];
#pragma unroll
      for (int nt = 0; nt < 4; ++nt) { ak[nt] = (f32x4)(0.f); av[nt] = (f32x4)(0.f); }
#pragma unroll
      for (int kc = 0; kc < 2; ++kc) {
        const f16x8 A = ld_cvt8(ent_emb + (size_t)tid * 64 + kc * 32 + lg * 8);
#pragma unroll
        for (int nt = 0; nt < 4; ++nt) {
          const f16x8 Bfk = *(const f16x8*)&Bk[((kc * 4 + nt) * 64 + lane) * 8];
          const f16x8 Bfv = *(const f16x8*)&Bv[((kc * 4 + nt) * 64 + lane) * 8];
          ak[nt] = __builtin_amdgcn_mfma_f32_16x16x32_f16(A, Bfk, ak[nt], 0, 0, 0);
          av[nt] = __builtin_amdgcn_mfma_f32_16x16x32_f16(A, Bfv, av[nt], 0, 0, 0);
        }
      }
#pragma unroll
      for (int nt = 0; nt < 4; ++nt) {
#pragma unroll
        for (int r = 0; r < 4; ++r) {
          const int rr = row0 - bs + lg * 4 + r;
          kkb[(size_t)rr * 64 + nt * 16 + l15] = f2h(ak[nt][r] + bsk[nt]);
          vvb[(size_t)rr * 64 + nt * 16 + l15] = f2h(av[nt][r] + bsv[nt]);
        }
      }
    }
    return;
  }

  // ---------------- B1 fold role (16 blocks) ----------------
  {
    float* Wa = (float*)smem;
    const int local = (int)blockIdx.x - npack - natt;
    for (int t = threadIdx.x; t < 4096; t += 512) Wa[t] = w_ent0[4096 + t];
    __syncthreads();
    const int t = threadIdx.x;
    if (t < 256) {
      B1[local * 256 + t] = w_ent0[local * 256 + t];
      const int m = local * 4 + (t >> 6);
      const int n = t & 63;
      float s = 0.f;
#pragma unroll 8
      for (int k = 0; k < 64; ++k) s = fmaf(rel_emb[m * 64 + k], Wa[k * 64 + n], s);
      B1[4096 + m * 64 + n] = s;
    }
  }
}

// ---------------------------------------------------------------------------
// K2 fused mid: per wave, 16 items (= 32 gemm1 rows).
// Phase 1 (gemm1): nv = [ent_emb[idx] | Xacc] @ B1 + b_ent0 -> per-wave LDS.
//   nvl row = 72 halves (payload 64 + pad 8): 144B row stride, 16B-aligned,
//   bank stride 36 == 4 mod 32 -> phase-2 b128 reads 2 lanes/bank (free).
//   [R9 BUG was stride 40 < 64 payload -> row overlap corruption.]
// Phase 2 (gemm2): v1 = [rel_emb[rsel] | nv0 | nv1] @ w0 + b0 (fp32 out).
// Same-wave DS ordering -> no barrier between phases.
// LDS: B1f 16KB + w0f 24KB + Lrel 8KB + nvl 18KB = 66KB -> 2 blocks/CU.
// ---------------------------------------------------------------------------
__global__ __launch_bounds__(256)
void k_mid(const _Float16* __restrict__ Xacc, const int* __restrict__ idx,
           const int* __restrict__ rsel_arr,
           const float* __restrict__ ent_emb, const float* __restrict__ rel_emb,
           const float* __restrict__ B1, const float* __restrict__ b_ent0,
           const float* __restrict__ w0, const float* __restrict__ b0,
           float* __restrict__ v1, int n_items)
{
  __shared__ _Float16 Bl1[4 * 4 * 64 * 8];          // 16KB (B1 frag)
  __shared__ _Float16 Bl2[6 * 4 * 64 * 8];          // 24KB (w0 frag)
  __shared__ _Float16 Lrel[64 * 64];                // 8KB
  __shared__ __align__(16) _Float16 nvl[4][32][72]; // 18KB (72 >= 64 payload!)

  for (int t = threadIdx.x; t < 8192; t += 256) {
    const int k = t >> 6, n = t & 63;
    const int kc = k >> 5, lg2 = (k >> 3) & 3, jj = k & 7;
    const int nt = n >> 4, ln = lg2 * 16 + (n & 15);
    Bl1[((kc * 4 + nt) * 64 + ln) * 8 + jj] = f2h(B1[t]);
  }
  for (int t = threadIdx.x; t < 12288; t += 256) {
    const int k = t >> 6, n = t & 63;
    const int kc = k >> 5, lg2 = (k >> 3) & 3, jj = k & 7;
    const int nt = n >> 4, ln = lg2 * 16 + (n & 15);
    Bl2[((kc * 4 + nt) * 64 + ln) * 8 + jj] = f2h(w0[t]);
  }
  for (int t = threadIdx.x; t < 4096; t += 256) Lrel[t] = f2h(rel_emb[t]);
  __syncthreads();

  const int lane = threadIdx.x & 63;
  const int wid = threadIdx.x >> 6;
  const int i0 = (blockIdx.x * 4 + wid) * 16;   // first item of this wave
  if (i0 >= n_items) return;
  const int row0 = i0 * 2;
  const int l15 = lane & 15, lg = lane >> 4;

  // ---------------- Phase 1: gemm1 for rows row0..row0+31 ----------------
  {
    const int e0 = idx[row0 + l15];
    const int e1 = idx[row0 + 16 + l15];
    float bs4[4];
#pragma unroll
    for (int nt = 0; nt < 4; ++nt) bs4[nt] = b_ent0[nt * 16 + l15];

    f32x4 acc0[4], acc1[4];
#pragma unroll
    for (int nt = 0; nt < 4; ++nt) { acc0[nt] = (f32x4)(0.f); acc1[nt] = (f32x4)(0.f); }

#pragma unroll
    for (int kc = 0; kc < 2; ++kc) {
      const f16x8 A0 = ld_cvt8(ent_emb + (size_t)e0 * 64 + kc * 32 + lg * 8);
      const f16x8 A1 = ld_cvt8(ent_emb + (size_t)e1 * 64 + kc * 32 + lg * 8);
#pragma unroll
      for (int nt = 0; nt < 4; ++nt) {
        const f16x8 Bf = *(const f16x8*)&Bl1[((kc * 4 + nt) * 64 + lane) * 8];
        acc0[nt] = __builtin_amdgcn_mfma_f32_16x16x32_f16(A0, Bf, acc0[nt], 0, 0, 0);
        acc1[nt] = __builtin_amdgcn_mfma_f32_16x16x32_f16(A1, Bf, acc1[nt], 0, 0, 0);
      }
    }
    const _Float16* x0 = Xacc + (size_t)(row0 + l15) * 64 + lg * 8;
    const _Float16* x1 = Xacc + (size_t)(row0 + 16 + l15) * 64 + lg * 8;
#pragma unroll
    for (int kc2 = 0; kc2 < 2; ++kc2) {
      const f16x8 A0 = *(const f16x8*)(x0 + kc2 * 32);
      const f16x8 A1 = *(const f16x8*)(x1 + kc2 * 32);
#pragma unroll
      for (int nt = 0; nt < 4; ++nt) {
        const f16x8 Bf = *(const f16x8*)&Bl1[(((kc2 + 2) * 4 + nt) * 64 + lane) * 8];
        acc0[nt] = __builtin_amdgcn_mfma_f32_16x16x32_f16(A0, Bf, acc0[nt], 0, 0, 0);
        acc1[nt] = __builtin_amdgcn_mfma_f32_16x16x32_f16(A1, Bf, acc1[nt], 0, 0, 0);
      }
    }

    // stage nv rows into per-wave LDS (lr = mt*16 + lg*4 + r)
#pragma unroll
    for (int mt = 0; mt < 2; ++mt) {
#pragma unroll
      for (int nt = 0; nt < 4; ++nt) {
#pragma unroll
        for (int r = 0; r < 4; ++r) {
          const int lr = mt * 16 + lg * 4 + r;
          const float v = (mt ? acc1[nt][r] : acc0[nt][r]) + bs4[nt];
          nvl[wid][lr][nt * 16 + l15] = f2h(v);
        }
      }
    }
  }

  // ---------------- Phase 2: gemm2 for items i0..i0+15 ----------------
  {
    const int rs = rsel_arr[i0 + l15];
    float bs4[4];
#pragma unroll
    for (int nt = 0; nt < 4; ++nt) bs4[nt] = b0[nt * 16 + l15];

    f32x4 acc[4];
#pragma unroll
    for (int nt = 0; nt < 4; ++nt) acc[nt] = (f32x4)(0.f);

#pragma unroll
    for (int kc = 0; kc < 6; ++kc) {
      f16x8 A;
      if (kc < 2) A = *(const f16x8*)&Lrel[rs * 64 + kc * 32 + lg * 8];
      else if (kc < 4) A = *(const f16x8*)&nvl[wid][2 * l15][(kc - 2) * 32 + lg * 8];
      else A = *(const f16x8*)&nvl[wid][2 * l15 + 1][(kc - 4) * 32 + lg * 8];
#pragma unroll
      for (int nt = 0; nt < 4; ++nt) {
        const f16x8 Bf = *(const f16x8*)&Bl2[((kc * 4 + nt) * 64 + lane) * 8];
        acc[nt] = __builtin_amdgcn_mfma_f32_16x16x32_f16(A, Bf, acc[nt], 0, 0, 0);
      }
    }

#pragma unroll
    for (int nt = 0; nt < 4; ++nt) {
#pragma unroll
      for (int r = 0; r < 4; ++r) {
        const int item = i0 + lg * 4 + r;
        v1[(size_t)item * 64 + nt * 16 + l15] = acc[nt][r] + bs4[nt];
      }
    }
  }
}

// ---------------------------------------------------------------------------
// K3 fused hop-2 (unchanged from R8, validated): mean -> nv2 MFMA -> ctx MFMA
// -> softmax + score. 4 b per block.
// ---------------------------------------------------------------------------
__global__ __launch_bounds__(256)
void k_hop2(const int* __restrict__ entity_pairs, const int* __restrict__ train_edges,
            const int* __restrict__ entity2edges, const float* __restrict__ v1,
            const float* __restrict__ ent_emb,
            const float* __restrict__ w_ent1, const float* __restrict__ b_ent1,
            const float* __restrict__ w1, const float* __restrict__ b1,
            const float* __restrict__ qbuf, const _Float16* __restrict__ kkb,
            const _Float16* __restrict__ vvb,
            const float* __restrict__ w_s, const float* __restrict__ b_s,
            float* __restrict__ out, int bs)
{
  __shared__ _Float16 Bwe[4 * 4 * 64 * 8];
  __shared__ _Float16 Bw1[6 * 4 * 64 * 8];
  __shared__ __align__(16) _Float16 Xl[8][64];
  __shared__ __align__(16) _Float16 nvl[8][64];
  __shared__ float ctxl[4][64];

  for (int t = threadIdx.x; t < 8192; t += 256) {
    const int k = t >> 6, n = t & 63;
    const int kc = k >> 5, lg2 = (k >> 3) & 3, jj = k & 7;
    const int nt = n >> 4, ln = lg2 * 16 + (n & 15);
    Bwe[((kc * 4 + nt) * 64 + ln) * 8 + jj] = f2h(w_ent1[t]);
  }
  for (int t = threadIdx.x; t < 12288; t += 256) {
    const int k = t >> 6, n = t & 63;
    const int kc = k >> 5, lg2 = (k >> 3) & 3, jj = k & 7;
    const int nt = n >> 4, ln = lg2 * 16 + (n & 15);
    Bw1[((kc * 4 + nt) * 64 + ln) * 8 + jj] = f2h(w1[t]);
  }

  const int lane = threadIdx.x & 63;
  const int wid = threadIdx.x >> 6;
  const int b0 = blockIdx.x * 4;
  const int myb = b0 + wid;
  const int l15 = lane & 15, lg = lane >> 4;

  if (myb < bs) {
    const int te = __builtin_amdgcn_readfirstlane(train_edges[myb]);
    const int n0 = __builtin_amdgcn_readfirstlane(entity_pairs[myb * 2 + 0]);
    const int n1 = __builtin_amdgcn_readfirstlane(entity_pairs[myb * 2 + 1]);
    const int myent = ((lane >> 4) & 1) ? n1 : n0;
    const int e = entity2edges[myent * 16 + (lane & 15)];
    const unsigned long long bal = __ballot(e != te);
    const int c0 = __popcll(bal & 0xFFFFull);
    const int c1 = __popcll(bal & 0xFFFF0000ull);
    const float* vbase = v1 + (size_t)myb * 33 * 64;
    float a0 = 0.f, a1 = 0.f;
#pragma unroll
    for (int s = 0; s < 16; ++s) {
      const float mA = (float)((bal >> s) & 1ull);
      const float mB = (float)((bal >> (s + 16)) & 1ull);
      a0 = fmaf(mA, vbase[s * 64 + lane], a0);
      a1 = fmaf(mB, vbase[(16 + s) * 64 + lane], a1);
    }
    Xl[wid * 2 + 0][lane] = f2h(a0 / (float)(c0 ? c0 : 1));
    Xl[wid * 2 + 1][lane] = f2h(a1 / (float)(c1 ? c1 : 1));
  }
  __syncthreads();

  if (wid == 0) {
    const int mm = l15 & 7;
    const int bm = min(b0 + (mm >> 1), bs - 1);
    const int side = mm & 1;
    const int ent = entity_pairs[bm * 2 + side];
    float bs4[4];
#pragma unroll
    for (int nt = 0; nt < 4; ++nt) bs4[nt] = b_ent1[nt * 16 + l15];
    f32x4 acc[4];
#pragma unroll
    for (int nt = 0; nt < 4; ++nt) acc[nt] = (f32x4)(0.f);
#pragma unroll
    for (int kc = 0; kc < 2; ++kc) {
      const f16x8 A = ld_cvt8(ent_emb + (size_t)ent * 64 + kc * 32 + lg * 8);
#pragma unroll
      for (int nt = 0; nt < 4; ++nt) {
        const f16x8 Bf = *(const f16x8*)&Bwe[((kc * 4 + nt) * 64 + lane) * 8];
        acc[nt] = __builtin_amdgcn_mfma_f32_16x16x32_f16(A, Bf, acc[nt], 0, 0, 0);
      }
    }
#pragma unroll
    for (int kc2 = 0; kc2 < 2; ++kc2) {
      const f16x8 A = *(const f16x8*)&Xl[mm][kc2 * 32 + lg * 8];
#pragma unroll
      for (int nt = 0; nt < 4; ++nt) {
        const f16x8 Bf = *(const f16x8*)&Bwe[(((kc2 + 2) * 4 + nt) * 64 + lane) * 8];
        acc[nt] = __builtin_amdgcn_mfma_f32_16x16x32_f16(A, Bf, acc[nt], 0, 0, 0);
      }
    }
#pragma unroll
    for (int nt = 0; nt < 4; ++nt) {
#pragma unroll
      for (int r = 0; r < 4; ++r) {
        const int m = lg * 4 + r;
        if (m < 8) nvl[m][nt * 16 + l15] = f2h(acc[nt][r] + bs4[nt]);
      }
    }
  }
  __syncthreads();

  if (wid == 0) {
    const int mb = min(b0 + (l15 & 3), bs - 1);
    float bs4[4];
#pragma unroll
    for (int nt = 0; nt < 4; ++nt) bs4[nt] = b1[nt * 16 + l15];
    f32x4 acc[4];
#pragma unroll
    for (int nt = 0; nt < 4; ++nt) acc[nt] = (f32x4)(0.f);
    const float* selfp = v1 + ((size_t)mb * 33 + 32) * 64;
#pragma unroll
    for (int kc = 0; kc < 6; ++kc) {
      f16x8 A;
      if (kc < 2) A = ld_cvt8(selfp + kc * 32 + lg * 8);
      else A = *(const f16x8*)&nvl[2 * (l15 & 3) + (kc >= 4 ? 1 : 0)][(kc & 1) * 32 + lg * 8];
#pragma unroll
      for (int nt = 0; nt < 4; ++nt) {
        const f16x8 Bf = *(const f16x8*)&Bw1[((kc * 4 + nt) * 64 + lane) * 8];
        acc[nt] = __builtin_amdgcn_mfma_f32_16x16x32_f16(A, Bf, acc[nt], 0, 0, 0);
      }
    }
#pragma unroll
    for (int nt = 0; nt < 4; ++nt) {
#pragma unroll
      for (int r = 0; r < 4; ++r) {
        const int m = lg * 4 + r;
        if (m < 4) ctxl[m][nt * 16 + l15] = acc[nt][r] + bs4[nt];
      }
    }
  }
  __syncthreads();

  if (myb >= bs) return;
  const float q = qbuf[(size_t)myb * 64 + lane];
  const float ctx = ctxl[wid][lane];
  float lgt[10], vvl[10];
#pragma unroll
  for (int k = 0; k < 10; ++k) {
    const float kk = (float)kkb[(size_t)(myb * 10 + k) * 64 + lane];
    vvl[k] = (float)vvb[(size_t)(myb * 10 + k) * 64 + lane];
    lgt[k] = wave_sum64(q * kk) * 0.125f;
  }
  float m = lgt[0];
#pragma unroll
  for (int k = 1; k < 10; ++k) m = fmaxf(m, lgt[k]);
  float den = 0.f;
  float att[10];
#pragma unroll
  for (int k = 0; k < 10; ++k) { att[k] = expf(lgt[k] - m); den += att[k]; }
  const float invden = 1.0f / den;
  float uatt = 0.f;
#pragma unroll
  for (int k = 0; k < 10; ++k) uatt = fmaf(att[k] * invden, vvl[k], uatt);

  const float sc = wave_sum64(uatt * ctx + ctx * w_s[lane]);
  if (lane == 0) out[myb] = sc + b_s[0];
}

extern "C" void kernel_launch(void* const* d_in, const int* in_sizes, int n_in,
                              void* d_out, int out_size, void* d_ws, size_t ws_size,
                              hipStream_t stream) {
  const int* relations     = (const int*)d_in[0];
  const int* entity_pairs  = (const int*)d_in[1];
  const int* train_edges   = (const int*)d_in[2];
  const int* user_ids      = (const int*)d_in[3];
  const int* top_k_ids     = (const int*)d_in[4];
  const int* entity2edges  = (const int*)d_in[5];
  const int* edge2entities = (const int*)d_in[6];
  const int* edge2relation = (const int*)d_in[7];
  const float* ent_emb  = (const float*)d_in[8];
  const float* rel_emb  = (const float*)d_in[9];
  const float* user_emb = (const float*)d_in[10];
  const float* w_ent0 = (const float*)d_in[11];
  const float* b_ent0 = (const float*)d_in[12];
  const float* w0     = (const float*)d_in[13];
  const float* b0     = (const float*)d_in[14];
  const float* w_ent1 = (const float*)d_in[15];
  const float* b_ent1 = (const float*)d_in[16];
  const float* w1     = (const float*)d_in[17];
  const float* b1     = (const float*)d_in[18];
  const float* wq  = (const float*)d_in[19];
  const float* bq  = (const float*)d_in[20];
  const float* wk  = (const float*)d_in[21];
  const float* bk  = (const float*)d_in[22];
  const float* wv  = (const float*)d_in[23];
  const float* bv  = (const float*)d_in[24];
  const float* w_s = (const float*)d_in[25];
  const float* b_s = (const float*)d_in[26];

  const int bs = in_sizes[0];
  const int n_items = bs * 33;        // 33792
  const int rows1 = 2 * n_items;      // 67584

  char* p = (char*)d_ws;
  float* v1 = (float*)p;          p += (size_t)n_items * 64 * 4;
  float* qbuf = (float*)p;        p += (size_t)bs * 64 * 4;
  float* B1 = (float*)p;          p += 128 * 64 * 4;
  _Float16* Xacc1 = (_Float16*)p; p += (size_t)rows1 * 64 * 2;
  _Float16* kkb = (_Float16*)p;   p += (size_t)bs * 10 * 64 * 2;
  _Float16* vvb = (_Float16*)p;   p += (size_t)bs * 10 * 64 * 2;
  int* idx1 = (int*)p;            p += (size_t)rows1 * 4;
  int* rselA = (int*)p;

  const int npack = (bs * 4 + 7) / 8;            // 512
  const int natt = (bs * 11 + 127) / 128;        // 88
  const int nfront = npack + natt + 16;

  k_front<<<dim3(nfront), dim3(512), 0, stream>>>(
      relations, entity_pairs, train_edges, entity2edges, edge2entities,
      edge2relation, rel_emb, w_ent0, user_ids, top_k_ids, user_emb, ent_emb,
      wq, bq, wk, bk, wv, bv, Xacc1, idx1, rselA, B1, qbuf, kkb, vvb,
      bs, npack, natt);

  k_mid<<<dim3((n_items + 63) / 64), dim3(256), 0, stream>>>(
      Xacc1, idx1, rselA, ent_emb, rel_emb, B1, b_ent0, w0, b0, v1, n_items);

  k_hop2<<<dim3((bs + 3) / 4), dim3(256), 0, stream>>>(
      entity_pairs, train_edges, entity2edges, v1, ent_emb,
      w_ent1, b_ent1, w1, b1, qbuf, kkb, vvb, w_s, b_s, (float*)d_out, bs);
}

// Round 12
// 43.823 us; speedup vs baseline: 1.3817x; 1.3817x over previous
//
#include <hip/hip_runtime.h>
#include <hip/hip_fp16.h>
#include <math.h>

#define DEV static __device__ __forceinline__

typedef float f32x4 __attribute__((ext_vector_type(4)));
typedef _Float16 f16x8 __attribute__((ext_vector_type(8)));

DEV _Float16 f2h(float x) { return (_Float16)x; }

DEV f16x8 ld_cvt8(const float* __restrict__ p) {
  const float4 a = *(const float4*)p;
  const float4 b = *(const float4*)(p + 4);
  f16x8 r;
  r[0] = f2h(a.x); r[1] = f2h(a.y); r[2] = f2h(a.z); r[3] = f2h(a.w);
  r[4] = f2h(b.x); r[5] = f2h(b.y); r[6] = f2h(b.z); r[7] = f2h(b.w);
  return r;
}

DEV float wave_sum64(float v) {
  v += __shfl_xor(v, 32, 64);
  v += __shfl_xor(v, 16, 64);
  v += __shfl_xor(v, 8, 64);
  v += __shfl_xor(v, 4, 64);
  v += __shfl_xor(v, 2, 64);
  v += __shfl_xor(v, 1, 64);
  return v;
}

// Fragment convention (validated R5-R10):
//   A[m = l&15][k = kc*32 + (l>>4)*8 + j], B[k][n = l&15],
//   D[m = (l>>4)*4 + r][n = l&15].
// B frag layout (now in GLOBAL ws, L2-hot): frag[((kc*4+nt)*64 + lg*16 +
//   (n&15))*8 + jj] with kc=k>>5, lg=(k>>3)&3, jj=k&7, nt=n>>4.
DEV int frag_off(int k, int n) {
  const int kc = k >> 5, lg2 = (k >> 3) & 3, jj = k & 7;
  const int nt = n >> 4, ln = lg2 * 16 + (n & 15);
  return ((kc * 4 + nt) * 64 + ln) * 8 + jj;
}

// ---------------------------------------------------------------------------
// K1 fused: blocks [0,NPACK): pack | [NPACK,+NATT): q/K/V proj |
// tail 16 blocks: fold ALL weight matrices into fragment-layout ws arrays:
//   B1frag = frag([w_ent0[0:64]; rel_emb @ w_ent0[64:128]])  (8192)
//   w0frag (12288) | wefrag = frag(w_ent1) (8192) | w1frag (12288)
// pack/att roles unchanged from R8/R10 (validated).
// ---------------------------------------------------------------------------
__global__ __launch_bounds__(512)
void k_front(const int* __restrict__ relations, const int* __restrict__ entity_pairs,
             const int* __restrict__ train_edges,
             const int* __restrict__ entity2edges, const int* __restrict__ edge2entities,
             const int* __restrict__ edge2relation,
             const float* __restrict__ rel_emb, const float* __restrict__ w_ent0,
             const float* __restrict__ w0, const float* __restrict__ w_ent1,
             const float* __restrict__ w1,
             const int* __restrict__ user_ids, const int* __restrict__ top_k_ids,
             const float* __restrict__ user_emb, const float* __restrict__ ent_emb,
             const float* __restrict__ wq, const float* __restrict__ bq,
             const float* __restrict__ wk, const float* __restrict__ bk,
             const float* __restrict__ wv, const float* __restrict__ bv,
             _Float16* __restrict__ Xacc, int* __restrict__ idx,
             int* __restrict__ rsel_arr,
             _Float16* __restrict__ B1frag, _Float16* __restrict__ w0frag,
             _Float16* __restrict__ wefrag, _Float16* __restrict__ w1frag,
             float* __restrict__ qout, _Float16* __restrict__ kkb,
             _Float16* __restrict__ vvb, int bs, int npack, int natt)
{
  __shared__ __align__(16) unsigned char smem[24576];
  const int lane = threadIdx.x & 63;
  const int wid = threadIdx.x >> 6;

  if ((int)blockIdx.x < npack) {
    // ---------------- pack role (unchanged) ----------------
    const int w = blockIdx.x * 8 + wid;
    const int b = w >> 2;
    const int q = w & 3;
    if (b >= bs) return;

    const int te = __builtin_amdgcn_readfirstlane(train_edges[b]);
    const int n0p = __builtin_amdgcn_readfirstlane(entity_pairs[b * 2 + 0]);
    const int n1p = __builtin_amdgcn_readfirstlane(entity_pairs[b * 2 + 1]);

    const int l5 = lane & 31;
    const int ent0 = (l5 >> 4) ? n1p : n0p;
    const int e0 = entity2edges[ent0 * 16 + (l5 & 15)];
    const int r0 = edge2relation[e0];

    const int itemBase = b * 33;

    int na0[4], na1[4], nb0[4], nb1[4];
#pragma unroll
    for (int t = 0; t < 4; ++t) {
      const int j0 = q * 8 + 2 * t;
      const int ea = __builtin_amdgcn_readlane(e0, j0);
      const int eb = __builtin_amdgcn_readlane(e0, j0 + 1);
      na0[t] = __builtin_amdgcn_readfirstlane(edge2entities[ea * 2 + 0]);
      na1[t] = __builtin_amdgcn_readfirstlane(edge2entities[ea * 2 + 1]);
      nb0[t] = __builtin_amdgcn_readfirstlane(edge2entities[eb * 2 + 0]);
      nb1[t] = __builtin_amdgcn_readfirstlane(edge2entities[eb * 2 + 1]);
    }
    int e_[4];
#pragma unroll
    for (int t = 0; t < 4; ++t) {
      const int ent = (lane < 16) ? na0[t] : (lane < 32) ? na1[t]
                    : (lane < 48) ? nb0[t] : nb1[t];
      e_[t] = entity2edges[ent * 16 + (lane & 15)];
    }
    unsigned long long bal_[4];
    int r_[4];
#pragma unroll
    for (int t = 0; t < 4; ++t) {
      const bool keep = (e_[t] != te);
      bal_[t] = __ballot(keep);
      const int rr = edge2relation[e_[t]];
      r_[t] = keep ? rr : 64;
    }
#pragma unroll
    for (int t = 0; t < 4; ++t) {
      int ha0 = 0, ha1 = 0, hb0 = 0, hb1 = 0;
#pragma unroll
      for (int s = 0; s < 16; ++s) {
        ha0 += (__builtin_amdgcn_readlane(r_[t], s) == lane) ? 1 : 0;
        ha1 += (__builtin_amdgcn_readlane(r_[t], s + 16) == lane) ? 1 : 0;
        hb0 += (__builtin_amdgcn_readlane(r_[t], s + 32) == lane) ? 1 : 0;
        hb1 += (__builtin_amdgcn_readlane(r_[t], s + 48) == lane) ? 1 : 0;
      }
      const int ca0 = __popcll(bal_[t] & 0xFFFFull);
      const int ca1 = __popcll(bal_[t] & 0xFFFF0000ull);
      const int cb0 = __popcll(bal_[t] & 0xFFFF00000000ull);
      const int cb1 = __popcll(bal_[t] >> 48);
      const int j0 = q * 8 + 2 * t;
      const int it0 = itemBase + j0, it1 = it0 + 1;
      Xacc[(size_t)(2 * it0 + 0) * 64 + lane] = f2h((float)ha0 / (float)(ca0 ? ca0 : 1));
      Xacc[(size_t)(2 * it0 + 1) * 64 + lane] = f2h((float)ha1 / (float)(ca1 ? ca1 : 1));
      Xacc[(size_t)(2 * it1 + 0) * 64 + lane] = f2h((float)hb0 / (float)(cb0 ? cb0 : 1));
      Xacc[(size_t)(2 * it1 + 1) * 64 + lane] = f2h((float)hb1 / (float)(cb1 ? cb1 : 1));
      if (lane == 0) {
        idx[2 * it0 + 0] = na0[t]; idx[2 * it0 + 1] = na1[t];
        idx[2 * it1 + 0] = nb0[t]; idx[2 * it1 + 1] = nb1[t];
        rsel_arr[it0] = __builtin_amdgcn_readlane(r0, j0);
        rsel_arr[it1] = __builtin_amdgcn_readlane(r0, j0 + 1);
      }
    }
    if (q == 3) {
      const int it = itemBase + 32;
      const bool keep0 = (e0 != te);
      const unsigned long long bal0 = __ballot(keep0);
      const int r0m = keep0 ? r0 : 64;
      int h0 = 0, h1 = 0;
#pragma unroll
      for (int s = 0; s < 16; ++s) {
        h0 += (__builtin_amdgcn_readlane(r0m, s) == lane) ? 1 : 0;
        h1 += (__builtin_amdgcn_readlane(r0m, s + 16) == lane) ? 1 : 0;
      }
      const int c0 = __popcll(bal0 & 0xFFFFull);
      const int c1 = __popcll(bal0 & 0xFFFF0000ull);
      Xacc[(size_t)(2 * it + 0) * 64 + lane] = f2h((float)h0 / (float)(c0 ? c0 : 1));
      Xacc[(size_t)(2 * it + 1) * 64 + lane] = f2h((float)h1 / (float)(c1 ? c1 : 1));
      if (lane == 0) {
        idx[2 * it + 0] = n0p;
        idx[2 * it + 1] = n1p;
        rsel_arr[it] = relations[b];
      }
    }
    return;
  }

  if ((int)blockIdx.x < npack + natt) {
    // ---------------- attention q/K/V projection role (unchanged) ----------
    _Float16* Bq = (_Float16*)smem;
    _Float16* Bk = Bq + 4096;
    _Float16* Bv = Bq + 8192;
    for (int t = threadIdx.x; t < 4096; t += 512) {
      const int k = t >> 6, n = t & 63;
      const int off = frag_off(k, n);
      Bq[off] = f2h(wq[t]); Bk[off] = f2h(wk[t]); Bv[off] = f2h(wv[t]);
    }
    __syncthreads();

    const int row0 = (((int)blockIdx.x - npack) * 8 + wid) * 16;
    if (row0 >= bs * 11) return;
    const int l15 = lane & 15, lg = lane >> 4;

    if (row0 < bs) {
      const int uid = user_ids[row0 + l15];
      float bs4[4];
#pragma unroll
      for (int nt = 0; nt < 4; ++nt) bs4[nt] = bq[nt * 16 + l15];
      f32x4 acc[4];
#pragma unroll
      for (int nt = 0; nt < 4; ++nt) acc[nt] = (f32x4)(0.f);
#pragma unroll
      for (int kc = 0; kc < 2; ++kc) {
        const f16x8 A = ld_cvt8(user_emb + (size_t)uid * 64 + kc * 32 + lg * 8);
#pragma unroll
        for (int nt = 0; nt < 4; ++nt) {
          const f16x8 Bf = *(const f16x8*)&Bq[((kc * 4 + nt) * 64 + lane) * 8];
          acc[nt] = __builtin_amdgcn_mfma_f32_16x16x32_f16(A, Bf, acc[nt], 0, 0, 0);
        }
      }
#pragma unroll
      for (int nt = 0; nt < 4; ++nt)
#pragma unroll
        for (int r = 0; r < 4; ++r)
          qout[(size_t)(row0 + lg * 4 + r) * 64 + nt * 16 + l15] = acc[nt][r] + bs4[nt];
    } else {
      const int r2 = row0 - bs + l15;
      const int tid = top_k_ids[r2];
      float bsk[4], bsv[4];
#pragma unroll
      for (int nt = 0; nt < 4; ++nt) { bsk[nt] = bk[nt * 16 + l15]; bsv[nt] = bv[nt * 16 + l15]; }
      f32x4 ak[4], av[4];
#pragma unroll
      for (int nt = 0; nt < 4; ++nt) { ak[nt] = (f32x4)(0.f); av[nt] = (f32x4)(0.f); }
#pragma unroll
      for (int kc = 0; kc < 2; ++kc) {
        const f16x8 A = ld_cvt8(ent_emb + (size_t)tid * 64 + kc * 32 + lg * 8);
#pragma unroll
        for (int nt = 0; nt < 4; ++nt) {
          const f16x8 Bfk = *(const f16x8*)&Bk[((kc * 4 + nt) * 64 + lane) * 8];
          const f16x8 Bfv = *(const f16x8*)&Bv[((kc * 4 + nt) * 64 + lane) * 8];
          ak[nt] = __builtin_amdgcn_mfma_f32_16x16x32_f16(A, Bfk, ak[nt], 0, 0, 0);
          av[nt] = __builtin_amdgcn_mfma_f32_16x16x32_f16(A, Bfv, av[nt], 0, 0, 0);
        }
      }
#pragma unroll
      for (int nt = 0; nt < 4; ++nt) {
#pragma unroll
        for (int r = 0; r < 4; ++r) {
          const int rr = row0 - bs + lg * 4 + r;
          kkb[(size_t)rr * 64 + nt * 16 + l15] = f2h(ak[nt][r] + bsk[nt]);
          vvb[(size_t)rr * 64 + nt * 16 + l15] = f2h(av[nt][r] + bsv[nt]);
        }
      }
    }
    return;
  }

  // ---------------- fold role (16 blocks): frag-layout weight arrays -------
  {
    const int local = (int)blockIdx.x - npack - natt;  // 0..15
    if (local < 8) {
      // B1frag: [w_ent0[0:64] ; rel_emb @ w_ent0[64:128]] -> frag fp16
      for (int e = local * 512 + threadIdx.x; e < 8192; e += 8 * 512) {
        const int k = e >> 6, n = e & 63;
        float v;
        if (k < 64) {
          v = w_ent0[k * 64 + n];
        } else {
          const int m = k - 64;
          v = 0.f;
#pragma unroll 8
          for (int kk = 0; kk < 64; ++kk)
            v = fmaf(rel_emb[m * 64 + kk], w_ent0[(64 + kk) * 64 + n], v);
        }
        B1frag[frag_off(k, n)] = f2h(v);
      }
    } else {
      // permute copies: w0frag (12288) | wefrag (8192) | w1frag (12288)
      const int l2 = local - 8;
      for (int e = l2 * 512 + threadIdx.x; e < 32768; e += 8 * 512) {
        if (e < 12288) {
          w0frag[frag_off(e >> 6, e & 63)] = f2h(w0[e]);
        } else if (e < 20480) {
          const int t = e - 12288;
          wefrag[frag_off(t >> 6, t & 63)] = f2h(w_ent1[t]);
        } else {
          const int t = e - 20480;
          w1frag[frag_off(t >> 6, t & 63)] = f2h(w1[t]);
        }
      }
    }
  }
}

// ---------------------------------------------------------------------------
// K2 fused mid: per wave, 16 items (= 32 gemm1 rows).
// B fragments read from GLOBAL (L2-hot, coalesced 16B/lane) -> LDS is only
// Lrel (8KB) + nvl (18KB) = 26KB -> 6 blocks/CU, 24 waves/CU (vs R10's 8).
// Phase 1: nv = [ent_emb[idx] | Xacc] @ B1 + b_ent0 -> per-wave LDS (72-pad).
// Phase 2: v1 = [rel_emb[rsel] | nv0 | nv1] @ w0 + b0 (fp32 out).
// Same-wave DS ordering -> no barrier between phases.
// ---------------------------------------------------------------------------
__global__ __launch_bounds__(256)
void k_mid(const _Float16* __restrict__ Xacc, const int* __restrict__ idx,
           const int* __restrict__ rsel_arr,
           const float* __restrict__ ent_emb, const float* __restrict__ rel_emb,
           const _Float16* __restrict__ B1frag, const _Float16* __restrict__ w0frag,
           const float* __restrict__ b_ent0, const float* __restrict__ b0,
           float* __restrict__ v1, int n_items)
{
  __shared__ _Float16 Lrel[64 * 64];                // 8KB
  __shared__ __align__(16) _Float16 nvl[4][32][72]; // 18KB

  for (int t = threadIdx.x; t < 4096; t += 256) Lrel[t] = f2h(rel_emb[t]);
  __syncthreads();

  const int lane = threadIdx.x & 63;
  const int wid = threadIdx.x >> 6;
  const int i0 = (blockIdx.x * 4 + wid) * 16;   // first item of this wave
  if (i0 >= n_items) return;
  const int row0 = i0 * 2;
  const int l15 = lane & 15, lg = lane >> 4;

  // ---------------- Phase 1: gemm1 for rows row0..row0+31 ----------------
  {
    const int e0 = idx[row0 + l15];
    const int e1 = idx[row0 + 16 + l15];
    float bs4[4];
#pragma unroll
    for (int nt = 0; nt < 4; ++nt) bs4[nt] = b_ent0[nt * 16 + l15];

    f32x4 acc0[4], acc1[4];
#pragma unroll
    for (int nt = 0; nt < 4; ++nt) { acc0[nt] = (f32x4)(0.f); acc1[nt] = (f32x4)(0.f); }

#pragma unroll
    for (int kc = 0; kc < 2; ++kc) {
      const f16x8 A0 = ld_cvt8(ent_emb + (size_t)e0 * 64 + kc * 32 + lg * 8);
      const f16x8 A1 = ld_cvt8(ent_emb + (size_t)e1 * 64 + kc * 32 + lg * 8);
#pragma unroll
      for (int nt = 0; nt < 4; ++nt) {
        const f16x8 Bf = *(const f16x8*)&B1frag[((kc * 4 + nt) * 64 + lane) * 8];
        acc0[nt] = __builtin_amdgcn_mfma_f32_16x16x32_f16(A0, Bf, acc0[nt], 0, 0, 0);
        acc1[nt] = __builtin_amdgcn_mfma_f32_16x16x32_f16(A1, Bf, acc1[nt], 0, 0, 0);
      }
    }
    const _Float16* x0 = Xacc + (size_t)(row0 + l15) * 64 + lg * 8;
    const _Float16* x1 = Xacc + (size_t)(row0 + 16 + l15) * 64 + lg * 8;
#pragma unroll
    for (int kc2 = 0; kc2 < 2; ++kc2) {
      const f16x8 A0 = *(const f16x8*)(x0 + kc2 * 32);
      const f16x8 A1 = *(const f16x8*)(x1 + kc2 * 32);
#pragma unroll
      for (int nt = 0; nt < 4; ++nt) {
        const f16x8 Bf = *(const f16x8*)&B1frag[(((kc2 + 2) * 4 + nt) * 64 + lane) * 8];
        acc0[nt] = __builtin_amdgcn_mfma_f32_16x16x32_f16(A0, Bf, acc0[nt], 0, 0, 0);
        acc1[nt] = __builtin_amdgcn_mfma_f32_16x16x32_f16(A1, Bf, acc1[nt], 0, 0, 0);
      }
    }

    // stage nv rows into per-wave LDS (lr = mt*16 + lg*4 + r)
#pragma unroll
    for (int mt = 0; mt < 2; ++mt) {
#pragma unroll
      for (int nt = 0; nt < 4; ++nt) {
#pragma unroll
        for (int r = 0; r < 4; ++r) {
          const int lr = mt * 16 + lg * 4 + r;
          const float v = (mt ? acc1[nt][r] : acc0[nt][r]) + bs4[nt];
          nvl[wid][lr][nt * 16 + l15] = f2h(v);
        }
      }
    }
  }

  // ---------------- Phase 2: gemm2 for items i0..i0+15 ----------------
  {
    const int rs = rsel_arr[i0 + l15];
    float bs4[4];
#pragma unroll
    for (int nt = 0; nt < 4; ++nt) bs4[nt] = b0[nt * 16 + l15];

    f32x4 acc[4];
#pragma unroll
    for (int nt = 0; nt < 4; ++nt) acc[nt] = (f32x4)(0.f);

#pragma unroll
    for (int kc = 0; kc < 6; ++kc) {
      f16x8 A;
      if (kc < 2) A = *(const f16x8*)&Lrel[rs * 64 + kc * 32 + lg * 8];
      else if (kc < 4) A = *(const f16x8*)&nvl[wid][2 * l15][(kc - 2) * 32 + lg * 8];
      else A = *(const f16x8*)&nvl[wid][2 * l15 + 1][(kc - 4) * 32 + lg * 8];
#pragma unroll
      for (int nt = 0; nt < 4; ++nt) {
        const f16x8 Bf = *(const f16x8*)&w0frag[((kc * 4 + nt) * 64 + lane) * 8];
        acc[nt] = __builtin_amdgcn_mfma_f32_16x16x32_f16(A, Bf, acc[nt], 0, 0, 0);
      }
    }

#pragma unroll
    for (int nt = 0; nt < 4; ++nt) {
#pragma unroll
      for (int r = 0; r < 4; ++r) {
        const int item = i0 + lg * 4 + r;
        v1[(size_t)item * 64 + nt * 16 + l15] = acc[nt][r] + bs4[nt];
      }
    }
  }
}

// ---------------------------------------------------------------------------
// K3 fused hop-2: mean -> nv2 MFMA -> ctx MFMA -> softmax + score.
// B fragments (wefrag/w1frag) from GLOBAL; LDS only 5KB of staging.
// 4 b per block (unchanged structure otherwise, validated R8/R10).
// ---------------------------------------------------------------------------
__global__ __launch_bounds__(256)
void k_hop2(const int* __restrict__ entity_pairs, const int* __restrict__ train_edges,
            const int* __restrict__ entity2edges, const float* __restrict__ v1,
            const float* __restrict__ ent_emb,
            const _Float16* __restrict__ wefrag, const float* __restrict__ b_ent1,
            const _Float16* __restrict__ w1frag, const float* __restrict__ b1,
            const float* __restrict__ qbuf, const _Float16* __restrict__ kkb,
            const _Float16* __restrict__ vvb,
            const float* __restrict__ w_s, const float* __restrict__ b_s,
            float* __restrict__ out, int bs)
{
  __shared__ __align__(16) _Float16 Xl[8][64];
  __shared__ __align__(16) _Float16 nvl[8][64];
  __shared__ float ctxl[4][64];

  const int lane = threadIdx.x & 63;
  const int wid = threadIdx.x >> 6;
  const int b0 = blockIdx.x * 4;
  const int myb = b0 + wid;
  const int l15 = lane & 15, lg = lane >> 4;

  if (myb < bs) {
    const int te = __builtin_amdgcn_readfirstlane(train_edges[myb]);
    const int n0 = __builtin_amdgcn_readfirstlane(entity_pairs[myb * 2 + 0]);
    const int n1 = __builtin_amdgcn_readfirstlane(entity_pairs[myb * 2 + 1]);
    const int myent = ((lane >> 4) & 1) ? n1 : n0;
    const int e = entity2edges[myent * 16 + (lane & 15)];
    const unsigned long long bal = __ballot(e != te);
    const int c0 = __popcll(bal & 0xFFFFull);
    const int c1 = __popcll(bal & 0xFFFF0000ull);
    const float* vbase = v1 + (size_t)myb * 33 * 64;
    float a0 = 0.f, a1 = 0.f;
#pragma unroll
    for (int s = 0; s < 16; ++s) {
      const float mA = (float)((bal >> s) & 1ull);
      const float mB = (float)((bal >> (s + 16)) & 1ull);
      a0 = fmaf(mA, vbase[s * 64 + lane], a0);
      a1 = fmaf(mB, vbase[(16 + s) * 64 + lane], a1);
    }
    Xl[wid * 2 + 0][lane] = f2h(a0 / (float)(c0 ? c0 : 1));
    Xl[wid * 2 + 1][lane] = f2h(a1 / (float)(c1 ? c1 : 1));
  }
  __syncthreads();

  if (wid == 0) {
    const int mm = l15 & 7;
    const int bm = min(b0 + (mm >> 1), bs - 1);
    const int side = mm & 1;
    const int ent = entity_pairs[bm * 2 + side];
    float bs4[4];
#pragma unroll
    for (int nt = 0; nt < 4; ++nt) bs4[nt] = b_ent1[nt * 16 + l15];
    f32x4 acc[4];
#pragma unroll
    for (int nt = 0; nt < 4; ++nt) acc[nt] = (f32x4)(0.f);
#pragma unroll
    for (int kc = 0; kc < 2; ++kc) {
      const f16x8 A = ld_cvt8(ent_emb + (size_t)ent * 64 + kc * 32 + lg * 8);
#pragma unroll
      for (int nt = 0; nt < 4; ++nt) {
        const f16x8 Bf = *(const f16x8*)&wefrag[((kc * 4 + nt) * 64 + lane) * 8];
        acc[nt] = __builtin_amdgcn_mfma_f32_16x16x32_f16(A, Bf, acc[nt], 0, 0, 0);
      }
    }
#pragma unroll
    for (int kc2 = 0; kc2 < 2; ++kc2) {
      const f16x8 A = *(const f16x8*)&Xl[mm][kc2 * 32 + lg * 8];
#pragma unroll
      for (int nt = 0; nt < 4; ++nt) {
        const f16x8 Bf = *(const f16x8*)&wefrag[(((kc2 + 2) * 4 + nt) * 64 + lane) * 8];
        acc[nt] = __builtin_amdgcn_mfma_f32_16x16x32_f16(A, Bf, acc[nt], 0, 0, 0);
      }
    }
#pragma unroll
    for (int nt = 0; nt < 4; ++nt) {
#pragma unroll
      for (int r = 0; r < 4; ++r) {
        const int m = lg * 4 + r;
        if (m < 8) nvl[m][nt * 16 + l15] = f2h(acc[nt][r] + bs4[nt]);
      }
    }
  }
  __syncthreads();

  if (wid == 0) {
    const int mb = min(b0 + (l15 & 3), bs - 1);
    float bs4[4];
#pragma unroll
    for (int nt = 0; nt < 4; ++nt) bs4[nt] = b1[nt * 16 + l15];
    f32x4 acc[4];
#pragma unroll
    for (int nt = 0; nt < 4; ++nt) acc[nt] = (f32x4)(0.f);
    const float* selfp = v1 + ((size_t)mb * 33 + 32) * 64;
#pragma unroll
    for (int kc = 0; kc < 6; ++kc) {
      f16x8 A;
      if (kc < 2) A = ld_cvt8(selfp + kc * 32 + lg * 8);
      else A = *(const f16x8*)&nvl[2 * (l15 & 3) + (kc >= 4 ? 1 : 0)][(kc & 1) * 32 + lg * 8];
#pragma unroll
      for (int nt = 0; nt < 4; ++nt) {
        const f16x8 Bf = *(const f16x8*)&w1frag[((kc * 4 + nt) * 64 + lane) * 8];
        acc[nt] = __builtin_amdgcn_mfma_f32_16x16x32_f16(A, Bf, acc[nt], 0, 0, 0);
      }
    }
#pragma unroll
    for (int nt = 0; nt < 4; ++nt) {
#pragma unroll
      for (int r = 0; r < 4; ++r) {
        const int m = lg * 4 + r;
        if (m < 4) ctxl[m][nt * 16 + l15] = acc[nt][r] + bs4[nt];
      }
    }
  }
  __syncthreads();

  if (myb >= bs) return;
  const float q = qbuf[(size_t)myb * 64 + lane];
  const float ctx = ctxl[wid][lane];
  float lgt[10], vvl[10];
#pragma unroll
  for (int k = 0; k < 10; ++k) {
    const float kk = (float)kkb[(size_t)(myb * 10 + k) * 64 + lane];
    vvl[k] = (float)vvb[(size_t)(myb * 10 + k) * 64 + lane];
    lgt[k] = wave_sum64(q * kk) * 0.125f;
  }
  float m = lgt[0];
#pragma unroll
  for (int k = 1; k < 10; ++k) m = fmaxf(m, lgt[k]);
  float den = 0.f;
  float att[10];
#pragma unroll
  for (int k = 0; k < 10; ++k) { att[k] = expf(lgt[k] - m); den += att[k]; }
  const float invden = 1.0f / den;
  float uatt = 0.f;
#pragma unroll
  for (int k = 0; k < 10; ++k) uatt = fmaf(att[k] * invden, vvl[k], uatt);

  const float sc = wave_sum64(uatt * ctx + ctx * w_s[lane]);
  if (lane == 0) out[myb] = sc + b_s[0];
}

extern "C" void kernel_launch(void* const* d_in, const int* in_sizes, int n_in,
                              void* d_out, int out_size, void* d_ws, size_t ws_size,
                              hipStream_t stream) {
  const int* relations     = (const int*)d_in[0];
  const int* entity_pairs  = (const int*)d_in[1];
  const int* train_edges   = (const int*)d_in[2];
  const int* user_ids      = (const int*)d_in[3];
  const int* top_k_ids     = (const int*)d_in[4];
  const int* entity2edges  = (const int*)d_in[5];
  const int* edge2entities = (const int*)d_in[6];
  const int* edge2relation = (const int*)d_in[7];
  const float* ent_emb  = (const float*)d_in[8];
  const float* rel_emb  = (const float*)d_in[9];
  const float* user_emb = (const float*)d_in[10];
  const float* w_ent0 = (const float*)d_in[11];
  const float* b_ent0 = (const float*)d_in[12];
  const float* w0     = (const float*)d_in[13];
  const float* b0     = (const float*)d_in[14];
  const float* w_ent1 = (const float*)d_in[15];
  const float* b_ent1 = (const float*)d_in[16];
  const float* w1     = (const float*)d_in[17];
  const float* b1     = (const float*)d_in[18];
  const float* wq  = (const float*)d_in[19];
  const float* bq  = (const float*)d_in[20];
  const float* wk  = (const float*)d_in[21];
  const float* bk  = (const float*)d_in[22];
  const float* wv  = (const float*)d_in[23];
  const float* bv  = (const float*)d_in[24];
  const float* w_s = (const float*)d_in[25];
  const float* b_s = (const float*)d_in[26];

  const int bs = in_sizes[0];
  const int n_items = bs * 33;        // 33792
  const int rows1 = 2 * n_items;      // 67584

  char* p = (char*)d_ws;
  float* v1 = (float*)p;            p += (size_t)n_items * 64 * 4;
  float* qbuf = (float*)p;          p += (size_t)bs * 64 * 4;
  _Float16* Xacc1 = (_Float16*)p;   p += (size_t)rows1 * 64 * 2;
  _Float16* kkb = (_Float16*)p;     p += (size_t)bs * 10 * 64 * 2;
  _Float16* vvb = (_Float16*)p;     p += (size_t)bs * 10 * 64 * 2;
  _Float16* B1frag = (_Float16*)p;  p += 8192 * 2;
  _Float16* w0frag = (_Float16*)p;  p += 12288 * 2;
  _Float16* wefrag = (_Float16*)p;  p += 8192 * 2;
  _Float16* w1frag = (_Float16*)p;  p += 12288 * 2;
  int* idx1 = (int*)p;              p += (size_t)rows1 * 4;
  int* rselA = (int*)p;

  const int npack = (bs * 4 + 7) / 8;            // 512
  const int natt = (bs * 11 + 127) / 128;        // 88
  const int nfront = npack + natt + 16;

  k_front<<<dim3(nfront), dim3(512), 0, stream>>>(
      relations, entity_pairs, train_edges, entity2edges, edge2entities,
      edge2relation, rel_emb, w_ent0, w0, w_ent1, w1,
      user_ids, top_k_ids, user_emb, ent_emb,
      wq, bq, wk, bk, wv, bv, Xacc1, idx1, rselA,
      B1frag, w0frag, wefrag, w1frag, qbuf, kkb, vvb,
      bs, npack, natt);

  k_mid<<<dim3((n_items + 63) / 64), dim3(256), 0, stream>>>(
      Xacc1, idx1, rselA, ent_emb, rel_emb, B1frag, w0frag,
      b_ent0, b0, v1, n_items);

  k_hop2<<<dim3((bs + 3) / 4), dim3(256), 0, stream>>>(
      entity_pairs, train_edges, entity2edges, v1, ent_emb,
      wefrag, b_ent1, w1frag, b1, qbuf, kkb, vvb, w_s, b_s,
      (float*)d_out, bs);
}